// Round 8
// baseline (115.207 us; speedup 1.0000x reference)
//
#include <hip/hip_runtime.h>

#define GQ   8192            // bs(32) * Gn(256)
#define WPB  2               // waves per block (2 consecutive groups share 128B lines)

// Wave-local LDS fence (SIMM is wave-private; no block barriers anywhere).
#define LDS_FENCE() asm volatile("s_waitcnt lgkmcnt(0)" ::: "memory")

// ---- DPP helpers: cross-lane adds on the VALU pipe (no LDS/DS usage) -------
template <int CTRL>
__device__ __forceinline__ float dpp_add(float x) {
    // x + dpp_move(x); OOB source lanes contribute 0 (old=0, bound_ctrl=true).
    int t = __builtin_amdgcn_update_dpp(0, __float_as_int(x), CTRL, 0xf, 0xf, true);
    return x + __int_as_float(t);
}
__device__ __forceinline__ float wave_sum64(float x) {
    x = dpp_add<0x111>(x);   // row_shr:1
    x = dpp_add<0x112>(x);   // row_shr:2
    x = dpp_add<0x114>(x);   // row_shr:4
    x = dpp_add<0x118>(x);   // row_shr:8  -> lane 15 of each row16 = row sum
    x = dpp_add<0x142>(x);   // row_bcast:15
    x = dpp_add<0x143>(x);   // row_bcast:31 -> lane 63 = full 64-lane sum
    return x;
}
__device__ __forceinline__ float row_sum16(float x) {
    x = dpp_add<0x111>(x);
    x = dpp_add<0x112>(x);
    x = dpp_add<0x114>(x);
    x = dpp_add<0x118>(x);   // lane 15 = sum of lanes 0..15
    return x;
}
__device__ __forceinline__ float rdlane_f(float x, int lane) {
    return __int_as_float(__builtin_amdgcn_readlane(__float_as_int(x), lane));
}

// One wave per group. Lane l owns channels (l, l+64) in registers. All
// cross-lane math (dup-check, pair dots, reductions) on VALU via DPP/readlane;
// the only LDS use is a 44-float wave-private SIMM exchange.
__global__ __launch_bounds__(64 * WPB, 4) void group_loss_kernel(
    const int*   __restrict__ labs,   // [G*16]
    const float* __restrict__ feats,  // [32,128,256,16]
    const int*   __restrict__ idxs,   // [G*16]
    const float* __restrict__ ctx,    // [128]
    float2* __restrict__ ws)          // [G] {gl*gv, gv}
{
    __shared__ float SH[WPB * 48];            // 44-float SIMM per wave + pad

    const int l  = threadIdx.x & 63;
    const int wu = threadIdx.x >> 6;
    float* SIMM = SH + wu * 48;

    const int blk = blockIdx.x;
    // XCD blk&7 owns groups [x<<10,(x+1)<<10); block = 2 consecutive groups
    const int g  = ((blk & 7) << 10) | ((blk >> 3) << 1) | wu;
    const int b  = g >> 8;
    const int gn = g & 255;
    const long fbase = (long)b * (128 * 256 * 16) + (long)gn * 16;

    // ---- feature columns straight to registers (lane l -> channels l, l+64)
    const float* gp0 = feats + fbase + (long)l * 4096;
    const float* gp1 = gp0 + 64 * 4096;
    float4 A[4], B[4];
    #pragma unroll
    for (int q = 0; q < 4; ++q) A[q] = *(const float4*)(gp0 + q * 4);
    #pragma unroll
    for (int q = 0; q < 4; ++q) B[q] = *(const float4*)(gp1 + q * 4);
    const float cx0 = ctx[l], cx1 = ctx[l + 64];
    float fa[16], fb[16];
    #pragma unroll
    for (int q = 0; q < 4; ++q) {
        fa[4*q+0] = A[q].x; fa[4*q+1] = A[q].y; fa[4*q+2] = A[q].z; fa[4*q+3] = A[q].w;
        fb[4*q+0] = B[q].x; fb[4*q+1] = B[q].y; fb[4*q+2] = B[q].z; fb[4*q+3] = B[q].w;
    }

    // ---- labels/indices: lanes 0..15 hold sample s=l -----------------------
    int myidx = -1, mylab = -2;
    if (l < 16) { myidx = idxs[g * 16 + l]; mylab = labs[g * 16 + l]; }

    // dup-check via readlane + ballot + scalar mask algebra (no DS pipe)
    unsigned long long dupm = 0ULL;
    #pragma unroll
    for (int j = 0; j < 15; ++j) {
        const int sj = __builtin_amdgcn_readlane(myidx, j);
        const unsigned long long eq = __ballot(myidx == sj);
        dupm |= (eq & ~((2ULL << j) - 1ULL));   // lanes > j matching sample j
    }
    const int u = __popcll(~dupm & 0xFFFFULL);  // distinct seed count

    const bool valid = l < u;                   // u<=16 -> lanes>=16 invalid
    const int bid = valid ? (mylab + 1) : 255;  // bucket 0=bg(-1), 1..8=fg

    int cnt[9];
    #pragma unroll
    for (int r = 0; r < 9; ++r) cnt[r] = __popcll(__ballot(bid == r));
    const bool has_bg = cnt[0] > 0;
    int fg_count = 0, pm = 0;
    #pragma unroll
    for (int r = 1; r < 9; ++r)
        if (cnt[r] > 0) { ++fg_count; pm |= 1 << r; }

    // ---- bucket sums: 16 uniform dispatches (readlane -> scalar switch) ----
    float m0[9] = {0,0,0,0,0,0,0,0,0};
    float m1[9] = {0,0,0,0,0,0,0,0,0};
    #pragma unroll
    for (int s = 0; s < 16; ++s) {
        if (s < u) {
            const int bs = __builtin_amdgcn_readlane(bid, s);
            switch (bs) {
                case 0: m0[0] += fa[s]; m1[0] += fb[s]; break;
                case 1: m0[1] += fa[s]; m1[1] += fb[s]; break;
                case 2: m0[2] += fa[s]; m1[2] += fb[s]; break;
                case 3: m0[3] += fa[s]; m1[3] += fb[s]; break;
                case 4: m0[4] += fa[s]; m1[4] += fb[s]; break;
                case 5: m0[5] += fa[s]; m1[5] += fb[s]; break;
                case 6: m0[6] += fa[s]; m1[6] += fb[s]; break;
                case 7: m0[7] += fa[s]; m1[7] += fb[s]; break;
                case 8: m0[8] += fa[s]; m1[8] += fb[s]; break;
            }
        }
    }
    #pragma unroll
    for (int r = 0; r < 9; ++r) {
        const float invc = 1.0f / (float)(cnt[r] > 0 ? cnt[r] : 1);
        m0[r] *= invc; m1[r] *= invc;
    }
    if (!has_bg) { m0[0] = cx0; m1[0] = cx1; }  // row 0 = context_compen

    // ---- 44 pair dots via DPP wave reductions (pure VALU) ------------------
    // pairs (i,j), 1<=i<=8, 0<=j<=i, p = i(i+1)/2 - 1 + j
    float mine = 0.0f;
    {
        int p = 0;
        #pragma unroll
        for (int i = 1; i <= 8; ++i) {
            #pragma unroll
            for (int j = 0; j <= i; ++j) {
                float x = m0[i] * m0[j] + m1[i] * m1[j];  // this lane's 2 channels
                x = wave_sum64(x);
                const float sv = rdlane_f(x, 63);          // uniform pair sum
                mine = (l == p) ? sv : mine;
                ++p;
            }
        }
    }
    mine *= 5.0f;                                // 1/T

    // ---- exchange 44 sims through wave-private LDS (only DS use) -----------
    if (l < 44) SIMM[l] = mine;
    LDS_FENCE();

    // ---- masked logsumexp per present fg row (lane r = row r) --------------
    float li_val = 0.0f;
    if (l >= 1 && l < 9 && ((pm >> l) & 1)) {
        const int r = l;
        float srow[9];
        #pragma unroll
        for (int j = 0; j < 9; ++j) {
            const int ii = (r > j) ? r : j;
            const int jj = (r > j) ? j : r;
            srow[j] = SIMM[ii * (ii + 1) / 2 - 1 + jj];
        }
        float vmax = srow[0];                    // col 0 (bg/ctx) always valid
        #pragma unroll
        for (int j = 1; j < 9; ++j)
            if ((pm >> j) & 1) vmax = fmaxf(vmax, srow[j]);
        float se = __expf(srow[0] - vmax);
        #pragma unroll
        for (int j = 1; j < 9; ++j)
            if ((pm >> j) & 1) se += __expf(srow[j] - vmax);
        li_val = vmax + __logf(se) - srow[r];
    }

    // ---- sum li over lanes 1..8 via DPP row-sum; lane 0 stores -------------
    const float ssum = row_sum16(li_val);        // lane 15 = sum lanes 0..15
    const float tot  = rdlane_f(ssum, 15);
    if (l == 0) {
        float2 r;
        r.x = tot / (float)(fg_count > 0 ? fg_count : 1);   // gl*gv
        r.y = (fg_count > 0) ? 1.0f : 0.0f;                 // gv
        ws[g] = r;
    }
}

// Deterministic 8192 -> 1 reduction
__global__ __launch_bounds__(1024) void reduce_kernel(
    const float2* __restrict__ ws, float* __restrict__ out)
{
    __shared__ float sa[1024], sb[1024];
    const int t = threadIdx.x;
    float a = 0.0f, b2 = 0.0f;
    for (int g = t; g < GQ; g += 1024) {
        float2 v = ws[g];
        a += v.x; b2 += v.y;
    }
    sa[t] = a; sb[t] = b2;
    __syncthreads();
    for (int off = 512; off > 0; off >>= 1) {
        if (t < off) { sa[t] += sa[t + off]; sb[t] += sb[t + off]; }
        __syncthreads();
    }
    if (t == 0) out[0] = 0.1f * (sa[0] / sb[0]);
}

extern "C" void kernel_launch(void* const* d_in, const int* in_sizes, int n_in,
                              void* d_out, int out_size, void* d_ws, size_t ws_size,
                              hipStream_t stream) {
    const int*   labs  = (const int*)d_in[0];    // proposal_instance_mask
    const float* feats = (const float*)d_in[1];  // grouped_features
    const int*   idxs  = (const int*)d_in[2];    // grouped_indices
    const float* ctx   = (const float*)d_in[3];  // context_compen
    float* out = (float*)d_out;
    float2* ws = (float2*)d_ws;

    group_loss_kernel<<<GQ / WPB, 64 * WPB, 0, stream>>>(labs, feats, idxs, ctx, ws);
    reduce_kernel<<<1, 1024, 0, stream>>>(ws, out);
}